// Round 4
// baseline (1240.849 us; speedup 1.0000x reference)
//
#include <hip/hip_runtime.h>
#include <cstdint>

// R8: both phases restructured from R7 counter evidence (absmax 0.0 kept by
// op-identical arithmetic, only reordered along legal dataflow).
//  - Phase 1 (was 390us, LDS-BW-bound): R4-proven W1-in-32-named-float4-regs
//    (lane=h) + x staged in LDS read as wave-broadcast b128 (near-zero LDS BW,
//    no conflicts). 256 thr, 4 waves x 16 rows, ~145 VGPR -> 3 waves/SIMD.
//  - Phase 2 (was 491us, VALUBusy 24.5%, 1 chain in flight): per 16-step
//    block, 3 spines: (1) m1+ballot spine -> 16 masks in SGPR uint32 pairs
//    (readfirstlane forces SALU extraction); (2) SIXTEEN INDEPENDENT c2
//    chains source-interleaved j-outer/i-inner (dep latency hidden, VALU
//    issue-bound); (3) m2/m3/c3 spine + batched register-staged stores.

#define TT  512
#define DIN 128
#define HH  64
#define OO  20

// ---------------------------------------------------------------------------
// Phase 1: cur1[row][h] = dot(x[row,:], W1[h,:]) + b1[h]
// Bit-exact per (row,h): a0 takes k=0,4,8,..., combine ((a0+a1)+(a2+a3))+b1.
// ---------------------------------------------------------------------------
__global__ __launch_bounds__(256) void snn_cur1(
    const float* __restrict__ x,      // (nrows, 128)
    const float* __restrict__ W1,     // (64, 128)
    const float* __restrict__ b1,     // (64,)
    float* __restrict__ cur1,         // (nrows, 64)
    int nrows)
{
    __shared__ float sx[64 * DIN];    // 32 KB: 64 rows of x
    const int tid  = threadIdx.x;
    const int lane = tid & 63;        // h
    const int wid  = tid >> 6;        // wave 0..3
    const int row0 = blockIdx.x * 64;

    // W1 row `lane` in 32 named float4 registers (R4-proven; no alloca)
    const float* w1p = W1 + lane * DIN;
#define W1LD(i) const float4 w##i = *reinterpret_cast<const float4*>(w1p + 4 * i);
    W1LD(0)  W1LD(1)  W1LD(2)  W1LD(3)  W1LD(4)  W1LD(5)  W1LD(6)  W1LD(7)
    W1LD(8)  W1LD(9)  W1LD(10) W1LD(11) W1LD(12) W1LD(13) W1LD(14) W1LD(15)
    W1LD(16) W1LD(17) W1LD(18) W1LD(19) W1LD(20) W1LD(21) W1LD(22) W1LD(23)
    W1LD(24) W1LD(25) W1LD(26) W1LD(27) W1LD(28) W1LD(29) W1LD(30) W1LD(31)
#undef W1LD
    const float bb1 = b1[lane];

    // stage 64 rows of x: 2048 float4, 8 per thread, coalesced
    const float* xb = x + (size_t)row0 * DIN;
#pragma unroll
    for (int p = 0; p < 8; ++p) {
        const int idx = tid + p * 256;        // 0..2047
        const int r   = idx >> 5;             // 0..63
        const int kq  = (idx & 31) << 2;      // 0..124
        *reinterpret_cast<float4*>(sx + r * DIN + kq) =
            *reinterpret_cast<const float4*>(xb + r * DIN + kq);
    }
    __syncthreads();

    // wave `wid` handles rows wid*16 .. wid*16+15; reads are wave-broadcast
    const float* xr0 = sx + wid * 16 * DIN;
    float*       cp  = cur1 + (size_t)(row0 + wid * 16) * HH + lane;

#pragma unroll 2
    for (int r = 0; r < 16; ++r) {
        const float* xr = xr0 + r * DIN;
        float a0 = 0.0f, a1 = 0.0f, a2 = 0.0f, a3 = 0.0f;
#define MAC4(i) { const float4 xk = *reinterpret_cast<const float4*>(xr + 4 * i); \
                  a0 = fmaf(xk.x, w##i.x, a0); a1 = fmaf(xk.y, w##i.y, a1);       \
                  a2 = fmaf(xk.z, w##i.z, a2); a3 = fmaf(xk.w, w##i.w, a3); }
        MAC4(0)  MAC4(1)  MAC4(2)  MAC4(3)  MAC4(4)  MAC4(5)  MAC4(6)  MAC4(7)
        MAC4(8)  MAC4(9)  MAC4(10) MAC4(11) MAC4(12) MAC4(13) MAC4(14) MAC4(15)
        MAC4(16) MAC4(17) MAC4(18) MAC4(19) MAC4(20) MAC4(21) MAC4(22) MAC4(23)
        MAC4(24) MAC4(25) MAC4(26) MAC4(27) MAC4(28) MAC4(29) MAC4(30) MAC4(31)
#undef MAC4
        cp[(size_t)r * HH] =
            __fadd_rn(__fadd_rn(__fadd_rn(a0, a1), __fadd_rn(a2, a3)), bb1);
    }
}

// ---------------------------------------------------------------------------
// Phase 2: serial recurrence, 16-step blocks, 3-spine schedule.
// ---------------------------------------------------------------------------
__global__ __launch_bounds__(64, 1) void snn_recur(
    const float* __restrict__ cur1,   // (B*T, 64)
    const float* __restrict__ beta1,
    const float* __restrict__ W2,     // (64, 64)
    const float* __restrict__ b2,
    const float* __restrict__ beta2,
    const float* __restrict__ W3,     // (20, 64)
    const float* __restrict__ b3,
    const float* __restrict__ beta3,
    float* __restrict__ out)          // (B, T, 20)
{
    __shared__ float sW3T[HH * 21];   // sW3T[j*21+o] = W3[o][j] (float both ways)
    const int lane = threadIdx.x;
    const int b    = blockIdx.x;

    // W2 row `lane` in 16 named float4 registers
    const float* w2p = W2 + lane * HH;
#define W2LD(i) const float4 u##i = *reinterpret_cast<const float4*>(w2p + 4 * i);
    W2LD(0)  W2LD(1)  W2LD(2)  W2LD(3)  W2LD(4)  W2LD(5)  W2LD(6)  W2LD(7)
    W2LD(8)  W2LD(9)  W2LD(10) W2LD(11) W2LD(12) W2LD(13) W2LD(14) W2LD(15)
#undef W2LD

    for (int oo = 0; oo < OO; ++oo) sW3T[lane * 21 + oo] = W3[oo * HH + lane];

    const float bt1 = fminf(fmaxf(beta1[lane], 0.0f), 1.0f);
    const float bb2 = b2[lane];
    const float bt2 = fminf(fmaxf(beta2[lane], 0.0f), 1.0f);
    const int   o   = (lane < OO) ? lane : 0;
    const float bb3 = b3[o];
    const float bt3 = fminf(fmaxf(beta3[o], 0.0f), 1.0f);
    float m1 = 0.0f, m2 = 0.0f, m3 = 0.0f;

    const float* cb   = cur1 + (size_t)b * TT * HH + lane;  // coalesced 256B/step
    float*       outb = out  + (size_t)b * TT * OO;
    const float* sW3row = sW3T + o;

    // spine 1: m1 update + ballot; masks forced into SGPRs (wave-uniform)
#define SP1(i, QV) { \
    const float r1v = (m1 > 1.0f) ? 1.0f : 0.0f; \
    m1 = __fsub_rn(__fadd_rn(__fmul_rn(bt1, m1), (QV)), r1v); \
    const unsigned long long s1m = __ballot(m1 > 1.0f); \
    ML##i = (unsigned int)__builtin_amdgcn_readfirstlane((int)(unsigned int)s1m); \
    MH##i = (unsigned int)__builtin_amdgcn_readfirstlane((int)(unsigned int)(s1m >> 32)); }

    // spine 2: 16 independent c2 chains, interleaved j-outer / chain-inner.
    // Per chain: ascending j, start bb2, c = fmaf(bit?1:0, w_j, c) — identical
    // ops to R7 (fmaf(1,w,c)=fadd_rn(w,c), fmaf(0,w,c)=c exactly).
#define CH16(MP, BIT, WV) \
    cc0  = fmaf(((MP##0  & (BIT)) ? 1.0f : 0.0f), (WV), cc0);  \
    cc1  = fmaf(((MP##1  & (BIT)) ? 1.0f : 0.0f), (WV), cc1);  \
    cc2  = fmaf(((MP##2  & (BIT)) ? 1.0f : 0.0f), (WV), cc2);  \
    cc3  = fmaf(((MP##3  & (BIT)) ? 1.0f : 0.0f), (WV), cc3);  \
    cc4  = fmaf(((MP##4  & (BIT)) ? 1.0f : 0.0f), (WV), cc4);  \
    cc5  = fmaf(((MP##5  & (BIT)) ? 1.0f : 0.0f), (WV), cc5);  \
    cc6  = fmaf(((MP##6  & (BIT)) ? 1.0f : 0.0f), (WV), cc6);  \
    cc7  = fmaf(((MP##7  & (BIT)) ? 1.0f : 0.0f), (WV), cc7);  \
    cc8  = fmaf(((MP##8  & (BIT)) ? 1.0f : 0.0f), (WV), cc8);  \
    cc9  = fmaf(((MP##9  & (BIT)) ? 1.0f : 0.0f), (WV), cc9);  \
    cc10 = fmaf(((MP##10 & (BIT)) ? 1.0f : 0.0f), (WV), cc10); \
    cc11 = fmaf(((MP##11 & (BIT)) ? 1.0f : 0.0f), (WV), cc11); \
    cc12 = fmaf(((MP##12 & (BIT)) ? 1.0f : 0.0f), (WV), cc12); \
    cc13 = fmaf(((MP##13 & (BIT)) ? 1.0f : 0.0f), (WV), cc13); \
    cc14 = fmaf(((MP##14 & (BIT)) ? 1.0f : 0.0f), (WV), cc14); \
    cc15 = fmaf(((MP##15 & (BIT)) ? 1.0f : 0.0f), (WV), cc15);
#define JL(j, WV) CH16(ML, 1u << (j), WV)
#define JH(j, WV) CH16(MH, 1u << ((j) - 32), WV)

    // spine 3: m2/m3 update + sparse c3 (ops identical to R7)
#define SP3(i, GV) { \
    const float r2v = (m2 > 1.0f) ? 1.0f : 0.0f; \
    m2 = __fsub_rn(__fadd_rn(__fmul_rn(bt2, m2), cc##i), r2v); \
    const unsigned long long s2m = __ballot(m2 > 1.0f); \
    float c3 = bb3; \
    if (s2m) { \
        unsigned long long mm = s2m; \
        int jj = __builtin_ctzll(mm); mm &= (mm - 1); \
        float vv = sW3row[jj * 21]; \
        while (mm) { \
            const int j2 = __builtin_ctzll(mm); mm &= (mm - 1); \
            const float v2 = sW3row[j2 * 21]; \
            c3 = __fadd_rn(c3, vv); \
            vv = v2; \
        } \
        c3 = __fadd_rn(c3, vv); \
    } \
    m3 = __fadd_rn(__fmul_rn(bt3, m3), c3); \
    GV = m3; }

    // prologue: steps 0..15 in flight
    float q0  = cb[0*HH],  q1  = cb[1*HH],  q2  = cb[2*HH],  q3  = cb[3*HH];
    float q4  = cb[4*HH],  q5  = cb[5*HH],  q6  = cb[6*HH],  q7  = cb[7*HH];
    float q8  = cb[8*HH],  q9  = cb[9*HH],  q10 = cb[10*HH], q11 = cb[11*HH];
    float q12 = cb[12*HH], q13 = cb[13*HH], q14 = cb[14*HH], q15 = cb[15*HH];

#pragma unroll 1
    for (int tb = 0; tb < TT; tb += 16) {
        // batch-issue next block's loads (oldest vmem ops of this iteration)
        float n0 = 0.f, n1 = 0.f, n2 = 0.f, n3 = 0.f, n4 = 0.f, n5 = 0.f,
              n6 = 0.f, n7 = 0.f, n8 = 0.f, n9 = 0.f, n10 = 0.f, n11 = 0.f,
              n12 = 0.f, n13 = 0.f, n14 = 0.f, n15 = 0.f;
        if (tb + 16 < TT) {
            const float* cn = cb + (size_t)(tb + 16) * HH;
            n0  = cn[0*HH];  n1  = cn[1*HH];  n2  = cn[2*HH];  n3  = cn[3*HH];
            n4  = cn[4*HH];  n5  = cn[5*HH];  n6  = cn[6*HH];  n7  = cn[7*HH];
            n8  = cn[8*HH];  n9  = cn[9*HH];  n10 = cn[10*HH]; n11 = cn[11*HH];
            n12 = cn[12*HH]; n13 = cn[13*HH]; n14 = cn[14*HH]; n15 = cn[15*HH];
        }

        // ---- spine 1: 16 m1 updates + masks
        unsigned int ML0, ML1, ML2, ML3, ML4, ML5, ML6, ML7,
                     ML8, ML9, ML10, ML11, ML12, ML13, ML14, ML15;
        unsigned int MH0, MH1, MH2, MH3, MH4, MH5, MH6, MH7,
                     MH8, MH9, MH10, MH11, MH12, MH13, MH14, MH15;
        SP1(0, q0)   SP1(1, q1)   SP1(2, q2)   SP1(3, q3)
        SP1(4, q4)   SP1(5, q5)   SP1(6, q6)   SP1(7, q7)
        SP1(8, q8)   SP1(9, q9)   SP1(10, q10) SP1(11, q11)
        SP1(12, q12) SP1(13, q13) SP1(14, q14) SP1(15, q15)

        // ---- spine 2: 16 interleaved c2 chains (j ascending per chain)
        float cc0 = bb2, cc1 = bb2, cc2 = bb2, cc3 = bb2,
              cc4 = bb2, cc5 = bb2, cc6 = bb2, cc7 = bb2,
              cc8 = bb2, cc9 = bb2, cc10 = bb2, cc11 = bb2,
              cc12 = bb2, cc13 = bb2, cc14 = bb2, cc15 = bb2;
        JL(0,  u0.x)  JL(1,  u0.y)  JL(2,  u0.z)  JL(3,  u0.w)
        JL(4,  u1.x)  JL(5,  u1.y)  JL(6,  u1.z)  JL(7,  u1.w)
        JL(8,  u2.x)  JL(9,  u2.y)  JL(10, u2.z)  JL(11, u2.w)
        JL(12, u3.x)  JL(13, u3.y)  JL(14, u3.z)  JL(15, u3.w)
        JL(16, u4.x)  JL(17, u4.y)  JL(18, u4.z)  JL(19, u4.w)
        JL(20, u5.x)  JL(21, u5.y)  JL(22, u5.z)  JL(23, u5.w)
        JL(24, u6.x)  JL(25, u6.y)  JL(26, u6.z)  JL(27, u6.w)
        JL(28, u7.x)  JL(29, u7.y)  JL(30, u7.z)  JL(31, u7.w)
        JH(32, u8.x)  JH(33, u8.y)  JH(34, u8.z)  JH(35, u8.w)
        JH(36, u9.x)  JH(37, u9.y)  JH(38, u9.z)  JH(39, u9.w)
        JH(40, u10.x) JH(41, u10.y) JH(42, u10.z) JH(43, u10.w)
        JH(44, u11.x) JH(45, u11.y) JH(46, u11.z) JH(47, u11.w)
        JH(48, u12.x) JH(49, u12.y) JH(50, u12.z) JH(51, u12.w)
        JH(52, u13.x) JH(53, u13.y) JH(54, u13.z) JH(55, u13.w)
        JH(56, u14.x) JH(57, u14.y) JH(58, u14.z) JH(59, u14.w)
        JH(60, u15.x) JH(61, u15.y) JH(62, u15.z) JH(63, u15.w)

        // ---- spine 3: m2/m3 + staged outputs
        float g0, g1, g2, g3, g4, g5, g6, g7,
              g8, g9, g10, g11, g12, g13, g14, g15;
        SP3(0, g0)   SP3(1, g1)   SP3(2, g2)   SP3(3, g3)
        SP3(4, g4)   SP3(5, g5)   SP3(6, g6)   SP3(7, g7)
        SP3(8, g8)   SP3(9, g9)   SP3(10, g10) SP3(11, g11)
        SP3(12, g12) SP3(13, g13) SP3(14, g14) SP3(15, g15)

        // flush: 16 lane-guarded scalar stores (verified R4/R7 pattern)
        if (lane < OO) {
            float* op = outb + (size_t)tb * OO + lane;
            op[0*OO]  = g0;  op[1*OO]  = g1;  op[2*OO]  = g2;  op[3*OO]  = g3;
            op[4*OO]  = g4;  op[5*OO]  = g5;  op[6*OO]  = g6;  op[7*OO]  = g7;
            op[8*OO]  = g8;  op[9*OO]  = g9;  op[10*OO] = g10; op[11*OO] = g11;
            op[12*OO] = g12; op[13*OO] = g13; op[14*OO] = g14; op[15*OO] = g15;
        }

        q0 = n0;  q1 = n1;  q2 = n2;  q3 = n3;  q4 = n4;  q5 = n5;
        q6 = n6;  q7 = n7;  q8 = n8;  q9 = n9;  q10 = n10; q11 = n11;
        q12 = n12; q13 = n13; q14 = n14; q15 = n15;
    }
#undef SP3
#undef JH
#undef JL
#undef CH16
#undef SP1
}

// ---------------------------------------------------------------------------
// Fallback: harness-verified fused kernel (unchanged), used if ws too small.
// ---------------------------------------------------------------------------
__global__ __launch_bounds__(64, 1) void snn_fused(
    const float* __restrict__ x,
    const float* __restrict__ W1,
    const float* __restrict__ b1,
    const float* __restrict__ beta1,
    const float* __restrict__ W2,
    const float* __restrict__ b2,
    const float* __restrict__ beta2,
    const float* __restrict__ W3,
    const float* __restrict__ b3,
    const float* __restrict__ beta3,
    float* __restrict__ out)
{
    __shared__ float sW2T[HH * 65];
    __shared__ float sW3T[HH * 21];
    __shared__ float sx[8 * DIN];

    const int lane = threadIdx.x;
    const int b    = blockIdx.x;

    const float* w1p = W1 + lane * DIN;
#define W1LD(i) const float4 w##i = *reinterpret_cast<const float4*>(w1p + 4 * i);
    W1LD(0)  W1LD(1)  W1LD(2)  W1LD(3)  W1LD(4)  W1LD(5)  W1LD(6)  W1LD(7)
    W1LD(8)  W1LD(9)  W1LD(10) W1LD(11) W1LD(12) W1LD(13) W1LD(14) W1LD(15)
    W1LD(16) W1LD(17) W1LD(18) W1LD(19) W1LD(20) W1LD(21) W1LD(22) W1LD(23)
    W1LD(24) W1LD(25) W1LD(26) W1LD(27) W1LD(28) W1LD(29) W1LD(30) W1LD(31)
#undef W1LD

    for (int h = 0; h < HH; ++h)  sW2T[lane * 65 + h]  = W2[h * HH + lane];
    for (int oo = 0; oo < OO; ++oo) sW3T[lane * 21 + oo] = W3[oo * HH + lane];

    const float bb1 = b1[lane];
    const float bt1 = fminf(fmaxf(beta1[lane], 0.0f), 1.0f);
    const float bb2 = b2[lane];
    const float bt2 = fminf(fmaxf(beta2[lane], 0.0f), 1.0f);
    const int   o   = (lane < OO) ? lane : 0;
    const float bb3 = b3[o];
    const float bt3 = fminf(fmaxf(beta3[o], 0.0f), 1.0f);
    float m1 = 0.0f, m2 = 0.0f, m3 = 0.0f;

    const float* xb   = x   + (size_t)b * TT * DIN;
    float*       outb = out + (size_t)b * TT * OO;
    const float* sW2row = sW2T + lane;
    const float* sW3row = sW3T + o;

    const float4 v0 = *reinterpret_cast<const float4*>(xb + 0 * DIN + 4 * lane);
    const float4 v1 = *reinterpret_cast<const float4*>(xb + 2 * DIN + 4 * lane);
    float4 pr = *reinterpret_cast<const float4*>(xb + 4 * DIN + 4 * lane);
    float4 pf = *reinterpret_cast<const float4*>(xb + 6 * DIN + 4 * lane);
    *reinterpret_cast<float4*>(sx + 0 * DIN + 4 * lane) = v0;
    *reinterpret_cast<float4*>(sx + 2 * DIN + 4 * lane) = v1;

    for (int t = 0; t < TT; ++t) {
        const float* xr = sx + (t & 7) * DIN;
        float a0 = 0.0f, a1 = 0.0f, a2 = 0.0f, a3 = 0.0f;
#define MAC4(i) { const float4 xk = *reinterpret_cast<const float4*>(xr + 4 * i); \
                  a0 = fmaf(xk.x, w##i.x, a0); a1 = fmaf(xk.y, w##i.y, a1);       \
                  a2 = fmaf(xk.z, w##i.z, a2); a3 = fmaf(xk.w, w##i.w, a3); }
        MAC4(0)  MAC4(1)  MAC4(2)  MAC4(3)  MAC4(4)  MAC4(5)  MAC4(6)  MAC4(7)
        MAC4(8)  MAC4(9)  MAC4(10) MAC4(11) MAC4(12) MAC4(13) MAC4(14) MAC4(15)
        MAC4(16) MAC4(17) MAC4(18) MAC4(19) MAC4(20) MAC4(21) MAC4(22) MAC4(23)
        MAC4(24) MAC4(25) MAC4(26) MAC4(27) MAC4(28) MAC4(29) MAC4(30) MAC4(31)
#undef MAC4
        const float cur1 = __fadd_rn(__fadd_rn(__fadd_rn(a0, a1), __fadd_rn(a2, a3)), bb1);

        const float r1 = (m1 > 1.0f) ? 1.0f : 0.0f;
        m1 = __fsub_rn(__fadd_rn(__fmul_rn(bt1, m1), cur1), r1);
        const unsigned long long s1 = __ballot(m1 > 1.0f);

        float c2 = bb2;
        {
            unsigned long long mm = s1;
            if (mm) {
                int j = __builtin_ctzll(mm); mm &= (mm - 1);
                float v = sW2row[j * 65];
                while (mm) {
                    const int j2 = __builtin_ctzll(mm); mm &= (mm - 1);
                    const float v2 = sW2row[j2 * 65];
                    c2 = __fadd_rn(c2, v);
                    v = v2;
                }
                c2 = __fadd_rn(c2, v);
            }
        }
        const float r2 = (m2 > 1.0f) ? 1.0f : 0.0f;
        m2 = __fsub_rn(__fadd_rn(__fmul_rn(bt2, m2), c2), r2);
        const unsigned long long s2 = __ballot(m2 > 1.0f);

        float c3 = bb3;
        if (s2) {
            unsigned long long mm = s2;
            int j = __builtin_ctzll(mm); mm &= (mm - 1);
            float v = sW3row[j * 21];
            while (mm) {
                const int j2 = __builtin_ctzll(mm); mm &= (mm - 1);
                const float v2 = sW3row[j2 * 21];
                c3 = __fadd_rn(c3, v);
                v = v2;
            }
            c3 = __fadd_rn(c3, v);
        }
        m3 = __fadd_rn(__fmul_rn(bt3, m3), c3);
        if (lane < OO) outb[t * OO + lane] = m3;

        if (((t & 1) == 0) && (t + 4 < TT)) {
            *reinterpret_cast<float4*>(sx + ((t + 4) & 7) * DIN + 4 * lane) = pr;
            pr = pf;
            if (t + 8 < TT) {
                pf = *reinterpret_cast<const float4*>(xb + (t + 8) * DIN + 4 * lane);
            }
        }
    }
}

extern "C" void kernel_launch(void* const* d_in, const int* in_sizes, int n_in,
                              void* d_out, int out_size, void* d_ws, size_t ws_size,
                              hipStream_t stream) {
    const float* x     = (const float*)d_in[0];
    const float* W1    = (const float*)d_in[1];
    const float* b1    = (const float*)d_in[2];
    const float* beta1 = (const float*)d_in[3];
    const float* W2    = (const float*)d_in[4];
    const float* b2    = (const float*)d_in[5];
    const float* beta2 = (const float*)d_in[6];
    const float* W3    = (const float*)d_in[7];
    const float* b3    = (const float*)d_in[8];
    const float* beta3 = (const float*)d_in[9];

    const int B = in_sizes[0] / (TT * DIN);   // 1024
    const int nrows = B * TT;                 // divisible by 64 (TT=512)
    const size_t need = (size_t)nrows * HH * sizeof(float);  // 128 MiB at B=1024

    if (d_ws != nullptr && ws_size >= need) {
        snn_cur1<<<dim3(nrows / 64), dim3(256), 0, stream>>>(
            x, W1, b1, (float*)d_ws, nrows);
        snn_recur<<<dim3(B), dim3(64), 0, stream>>>(
            (const float*)d_ws, beta1, W2, b2, beta2, W3, b3, beta3,
            (float*)d_out);
    } else {
        snn_fused<<<dim3(B), dim3(64), 0, stream>>>(
            x, W1, b1, beta1, W2, b2, beta2, W3, b3, beta3, (float*)d_out);
    }
}

// Round 7
// 514.131 us; speedup vs baseline: 2.4135x; 2.4135x over previous
//
#include <hip/hip_runtime.h>
#include <cstdint>

// R11: identical resubmit of R10 (two consecutive container-level infra
// failures; the kernel has not executed since R8). Decomposition rationale:
// R8's null result (three different c2 implementations all ~2300-2440
// cyc/step) + R7's VGPR_Count=56 (compiler demoted named-register state) say
// the serial cost is NOT c2 compute and NOT fixable by source-level register
// scheduling. Split phase 2 along dataflow to isolate it:
//   snn_cur1 (R7-exact, ~390us verified) -> cur1
//   snn_spk1 (serial, tiny): m1 recurrence + ballot -> s1 masks (u64/step)
//   snn_cur2 (parallel): c2 = b2 + sparse W2 adds from masks, occupancy-hidden
//   snn_rec23 (serial, tiny): m2/m3 + rare c3 + batched stores
// All fp ops keep the verified operand order (absmax 0.0). c2 overwrites the
// cur1 buffer (consumed by then); ws need = 128MiB + 4MiB masks, with the
// proven R7 2-kernel path as fallback.

#define TT  512
#define DIN 128
#define HH  64
#define OO  20
#define S1P 132   // LDS row stride (floats) for 128-wide rows (R7 phase 1)

// ---------------------------------------------------------------------------
// Phase 1 (R7-exact): cur1[row][h] = dot(x[row,:], W1[h,:]) + b1[h]
// ---------------------------------------------------------------------------
__global__ __launch_bounds__(256, 1) void snn_cur1(
    const float* __restrict__ x,      // (nrows, 128)
    const float* __restrict__ W1,     // (64, 128)
    const float* __restrict__ b1,     // (64,)
    float* __restrict__ cur1,         // (nrows, 64)
    int nrows)
{
    __shared__ float sX[64 * S1P];
    __shared__ float sW[64 * S1P];
    const int tid  = threadIdx.x;
    const int row0 = blockIdx.x * 64;

    const float* xb = x + (size_t)row0 * DIN;
#pragma unroll
    for (int p = 0; p < 8; ++p) {
        const int idx = tid + p * 256;        // 0..2047
        const int r   = idx >> 5;             // 0..63
        const int kq  = (idx & 31) << 2;      // 0..124
        *reinterpret_cast<float4*>(sX + r * S1P + kq) =
            *reinterpret_cast<const float4*>(xb + r * DIN + kq);
        *reinterpret_cast<float4*>(sW + r * S1P + kq) =
            *reinterpret_cast<const float4*>(W1 + r * DIN + kq);
    }
    __syncthreads();

    const int hq = tid & 15;                  // h = hq + 16*i, i=0..3
    const int rq = tid >> 4;                  // rows rq*4 .. rq*4+3
    const float* xrow = sX + rq * 4 * S1P;
    const float* wrow = sW + hq * S1P;

#define DECLA(i) float4 A##i##0 = {0.f,0.f,0.f,0.f}, A##i##1 = {0.f,0.f,0.f,0.f}, \
                        A##i##2 = {0.f,0.f,0.f,0.f}, A##i##3 = {0.f,0.f,0.f,0.f};
    DECLA(0) DECLA(1) DECLA(2) DECLA(3)
#undef DECLA

#define PH1FMA(i, r) \
    A##i##r.x = fmaf(xv##r.x, wv##i.x, A##i##r.x); \
    A##i##r.y = fmaf(xv##r.y, wv##i.y, A##i##r.y); \
    A##i##r.z = fmaf(xv##r.z, wv##i.z, A##i##r.z); \
    A##i##r.w = fmaf(xv##r.w, wv##i.w, A##i##r.w);

#pragma unroll 4
    for (int c = 0; c < 32; ++c) {
        const int k0 = c << 2;
        const float4 xv0 = *reinterpret_cast<const float4*>(xrow + 0 * S1P + k0);
        const float4 xv1 = *reinterpret_cast<const float4*>(xrow + 1 * S1P + k0);
        const float4 xv2 = *reinterpret_cast<const float4*>(xrow + 2 * S1P + k0);
        const float4 xv3 = *reinterpret_cast<const float4*>(xrow + 3 * S1P + k0);
        const float4 wv0 = *reinterpret_cast<const float4*>(wrow + 0 * 16 * S1P + k0);
        const float4 wv1 = *reinterpret_cast<const float4*>(wrow + 1 * 16 * S1P + k0);
        const float4 wv2 = *reinterpret_cast<const float4*>(wrow + 2 * 16 * S1P + k0);
        const float4 wv3 = *reinterpret_cast<const float4*>(wrow + 3 * 16 * S1P + k0);
        PH1FMA(0,0) PH1FMA(0,1) PH1FMA(0,2) PH1FMA(0,3)
        PH1FMA(1,0) PH1FMA(1,1) PH1FMA(1,2) PH1FMA(1,3)
        PH1FMA(2,0) PH1FMA(2,1) PH1FMA(2,2) PH1FMA(2,3)
        PH1FMA(3,0) PH1FMA(3,1) PH1FMA(3,2) PH1FMA(3,3)
    }
#undef PH1FMA

    const float bh0 = b1[hq];
    const float bh1 = b1[hq + 16];
    const float bh2 = b1[hq + 32];
    const float bh3 = b1[hq + 48];

#define PH1OUT(i, r, BB) \
    cur1[(size_t)(row0 + rq * 4 + r) * HH + hq + 16 * i] = \
        __fadd_rn(__fadd_rn(__fadd_rn(A##i##r.x, A##i##r.y), \
                            __fadd_rn(A##i##r.z, A##i##r.w)), BB);
    PH1OUT(0,0,bh0) PH1OUT(0,1,bh0) PH1OUT(0,2,bh0) PH1OUT(0,3,bh0)
    PH1OUT(1,0,bh1) PH1OUT(1,1,bh1) PH1OUT(1,2,bh1) PH1OUT(1,3,bh1)
    PH1OUT(2,0,bh2) PH1OUT(2,1,bh2) PH1OUT(2,2,bh2) PH1OUT(2,3,bh2)
    PH1OUT(3,0,bh3) PH1OUT(3,1,bh3) PH1OUT(3,2,bh3) PH1OUT(3,3,bh3)
#undef PH1OUT
}

// ---------------------------------------------------------------------------
// Kernel A: m1 recurrence + ballot -> masks[b][t] (u64). Serial over t.
// ---------------------------------------------------------------------------
__global__ __launch_bounds__(64) void snn_spk1(
    const float* __restrict__ cur1,   // (B*T, 64)
    const float* __restrict__ beta1,
    unsigned long long* __restrict__ masks)  // (B*T,)
{
    const int lane = threadIdx.x;
    const int b    = blockIdx.x;
    const float bt1 = fminf(fmaxf(beta1[lane], 0.0f), 1.0f);
    float m1 = 0.0f;

    const float* cb = cur1 + (size_t)b * TT * HH + lane;
    unsigned long long* mb = masks + (size_t)b * TT;

#define ASTEP(i, QV) { \
    const float r1v = (m1 > 1.0f) ? 1.0f : 0.0f; \
    m1 = __fsub_rn(__fadd_rn(__fmul_rn(bt1, m1), (QV)), r1v); \
    const unsigned long long s1m = __ballot(m1 > 1.0f); \
    if (lane == (i)) msk = s1m; }

    float q0  = cb[0*HH],  q1  = cb[1*HH],  q2  = cb[2*HH],  q3  = cb[3*HH];
    float q4  = cb[4*HH],  q5  = cb[5*HH],  q6  = cb[6*HH],  q7  = cb[7*HH];
    float q8  = cb[8*HH],  q9  = cb[9*HH],  q10 = cb[10*HH], q11 = cb[11*HH];
    float q12 = cb[12*HH], q13 = cb[13*HH], q14 = cb[14*HH], q15 = cb[15*HH];

#pragma unroll 1
    for (int tb = 0; tb < TT; tb += 16) {
        float n0 = 0.f, n1 = 0.f, n2 = 0.f, n3 = 0.f, n4 = 0.f, n5 = 0.f,
              n6 = 0.f, n7 = 0.f, n8 = 0.f, n9 = 0.f, n10 = 0.f, n11 = 0.f,
              n12 = 0.f, n13 = 0.f, n14 = 0.f, n15 = 0.f;
        if (tb + 16 < TT) {
            const float* cn = cb + (size_t)(tb + 16) * HH;
            n0  = cn[0*HH];  n1  = cn[1*HH];  n2  = cn[2*HH];  n3  = cn[3*HH];
            n4  = cn[4*HH];  n5  = cn[5*HH];  n6  = cn[6*HH];  n7  = cn[7*HH];
            n8  = cn[8*HH];  n9  = cn[9*HH];  n10 = cn[10*HH]; n11 = cn[11*HH];
            n12 = cn[12*HH]; n13 = cn[13*HH]; n14 = cn[14*HH]; n15 = cn[15*HH];
        }

        unsigned long long msk = 0ull;
        ASTEP(0, q0)   ASTEP(1, q1)   ASTEP(2, q2)   ASTEP(3, q3)
        ASTEP(4, q4)   ASTEP(5, q5)   ASTEP(6, q6)   ASTEP(7, q7)
        ASTEP(8, q8)   ASTEP(9, q9)   ASTEP(10, q10) ASTEP(11, q11)
        ASTEP(12, q12) ASTEP(13, q13) ASTEP(14, q14) ASTEP(15, q15)

        if (lane < 16) mb[tb + lane] = msk;   // 128B coalesced

        q0 = n0;  q1 = n1;  q2 = n2;  q3 = n3;  q4 = n4;  q5 = n5;
        q6 = n6;  q7 = n7;  q8 = n8;  q9 = n9;  q10 = n10; q11 = n11;
        q12 = n12; q13 = n13; q14 = n14; q15 = n15;
    }
#undef ASTEP
}

// ---------------------------------------------------------------------------
// Kernel B: c2[row][h] = b2[h] + sum_{j in mask(row)} W2[h][j], ascending j.
// Fully parallel over rows; SGPR masks + conflict-free LDS; same add order
// as the verified sparse path (start b2, ascending j) -> bit-identical.
// ---------------------------------------------------------------------------
__global__ __launch_bounds__(256) void snn_cur2(
    const unsigned long long* __restrict__ masks,
    const float* __restrict__ W2,     // (64, 64)
    const float* __restrict__ b2,
    float* __restrict__ c2,           // (B*T, 64) — overwrites cur1 buffer
    int nrows)
{
    __shared__ float sW2T[HH * 65];   // sW2T[j*65+h] = W2[h][j]
    const int tid  = threadIdx.x;
    const int lane = tid & 63;
    const int wid  = tid >> 6;

    // coalesced W2 read (h=idx>>6 fixed per wave-row, j=idx&63 consecutive);
    // LDS write j*65+h: 65%32==1 -> bank (j+h)%32, 2 lanes/bank = conflict-free
#pragma unroll
    for (int p = 0; p < 16; ++p) {
        const int idx = tid + p * 256;        // 0..4095
        const int h = idx >> 6, j = idx & 63;
        sW2T[j * 65 + h] = W2[h * HH + j];
    }
    __syncthreads();

    const float bb2 = b2[lane];
    const int row0 = blockIdx.x * 128 + wid * 32;
    const unsigned long long* mb = masks + row0;
    float* cp = c2 + (size_t)row0 * HH + lane;

    unsigned long long mk_next = mb[0];
#pragma unroll 1
    for (int r = 0; r < 32; ++r) {
        const unsigned long long mk = mk_next;
        if (r + 1 < 32) mk_next = mb[r + 1];
        unsigned int lo = (unsigned int)__builtin_amdgcn_readfirstlane(
            (int)(unsigned int)mk);
        unsigned int hi = (unsigned int)__builtin_amdgcn_readfirstlane(
            (int)(unsigned int)(mk >> 32));
        float c = bb2;
        while (lo) {
            const int j = __builtin_ctz(lo); lo &= lo - 1;
            c = __fadd_rn(c, sW2T[j * 65 + lane]);
        }
        while (hi) {
            const int j = __builtin_ctz(hi); hi &= hi - 1;
            c = __fadd_rn(c, sW2T[(j + 32) * 65 + lane]);
        }
        cp[(size_t)r * HH] = c;
    }
}

// ---------------------------------------------------------------------------
// Kernel C: m2/m3 recurrence + rare sparse c3 + batched stores. Serial over t.
// ---------------------------------------------------------------------------
__global__ __launch_bounds__(64) void snn_rec23(
    const float* __restrict__ c2buf,  // (B*T, 64), includes b2
    const float* __restrict__ beta2,
    const float* __restrict__ W3,     // (20, 64)
    const float* __restrict__ b3,
    const float* __restrict__ beta3,
    float* __restrict__ out)          // (B, T, 20)
{
    __shared__ float sW3T[HH * 21];   // sW3T[j*21+o] = W3[o][j]
    const int lane = threadIdx.x;
    const int b    = blockIdx.x;

    for (int oo = 0; oo < OO; ++oo) sW3T[lane * 21 + oo] = W3[oo * HH + lane];

    const float bt2 = fminf(fmaxf(beta2[lane], 0.0f), 1.0f);
    const int   o   = (lane < OO) ? lane : 0;
    const float bb3 = b3[o];
    const float bt3 = fminf(fmaxf(beta3[o], 0.0f), 1.0f);
    float m2 = 0.0f, m3 = 0.0f;

    const float* cb   = c2buf + (size_t)b * TT * HH + lane;
    float*       outb = out   + (size_t)b * TT * OO;
    const float* sW3row = sW3T + o;

#define CSTEP(i, QV, GV) { \
    const float r2v = (m2 > 1.0f) ? 1.0f : 0.0f; \
    m2 = __fsub_rn(__fadd_rn(__fmul_rn(bt2, m2), (QV)), r2v); \
    const unsigned long long s2m = __ballot(m2 > 1.0f); \
    float c3 = bb3; \
    if (s2m) { \
        unsigned long long mm = s2m; \
        int jj = __builtin_ctzll(mm); mm &= (mm - 1); \
        float vv = sW3row[jj * 21]; \
        while (mm) { \
            const int j2 = __builtin_ctzll(mm); mm &= (mm - 1); \
            const float v2 = sW3row[j2 * 21]; \
            c3 = __fadd_rn(c3, vv); \
            vv = v2; \
        } \
        c3 = __fadd_rn(c3, vv); \
    } \
    m3 = __fadd_rn(__fmul_rn(bt3, m3), c3); \
    GV = m3; }

    float q0  = cb[0*HH],  q1  = cb[1*HH],  q2  = cb[2*HH],  q3  = cb[3*HH];
    float q4  = cb[4*HH],  q5  = cb[5*HH],  q6  = cb[6*HH],  q7  = cb[7*HH];
    float q8  = cb[8*HH],  q9  = cb[9*HH],  q10 = cb[10*HH], q11 = cb[11*HH];
    float q12 = cb[12*HH], q13 = cb[13*HH], q14 = cb[14*HH], q15 = cb[15*HH];

#pragma unroll 1
    for (int tb = 0; tb < TT; tb += 16) {
        float n0 = 0.f, n1 = 0.f, n2 = 0.f, n3 = 0.f, n4 = 0.f, n5 = 0.f,
              n6 = 0.f, n7 = 0.f, n8 = 0.f, n9 = 0.f, n10 = 0.f, n11 = 0.f,
              n12 = 0.f, n13 = 0.f, n14 = 0.f, n15 = 0.f;
        if (tb + 16 < TT) {
            const float* cn = cb + (size_t)(tb + 16) * HH;
            n0  = cn[0*HH];  n1  = cn[1*HH];  n2  = cn[2*HH];  n3  = cn[3*HH];
            n4  = cn[4*HH];  n5  = cn[5*HH];  n6  = cn[6*HH];  n7  = cn[7*HH];
            n8  = cn[8*HH];  n9  = cn[9*HH];  n10 = cn[10*HH]; n11 = cn[11*HH];
            n12 = cn[12*HH]; n13 = cn[13*HH]; n14 = cn[14*HH]; n15 = cn[15*HH];
        }

        float g0, g1, g2, g3, g4, g5, g6, g7,
              g8, g9, g10, g11, g12, g13, g14, g15;
        CSTEP(0, q0, g0)   CSTEP(1, q1, g1)   CSTEP(2, q2, g2)   CSTEP(3, q3, g3)
        CSTEP(4, q4, g4)   CSTEP(5, q5, g5)   CSTEP(6, q6, g6)   CSTEP(7, q7, g7)
        CSTEP(8, q8, g8)   CSTEP(9, q9, g9)   CSTEP(10, q10, g10) CSTEP(11, q11, g11)
        CSTEP(12, q12, g12) CSTEP(13, q13, g13) CSTEP(14, q14, g14) CSTEP(15, q15, g15)

        if (lane < OO) {
            float* op = outb + (size_t)tb * OO + lane;
            op[0*OO]  = g0;  op[1*OO]  = g1;  op[2*OO]  = g2;  op[3*OO]  = g3;
            op[4*OO]  = g4;  op[5*OO]  = g5;  op[6*OO]  = g6;  op[7*OO]  = g7;
            op[8*OO]  = g8;  op[9*OO]  = g9;  op[10*OO] = g10; op[11*OO] = g11;
            op[12*OO] = g12; op[13*OO] = g13; op[14*OO] = g14; op[15*OO] = g15;
        }

        q0 = n0;  q1 = n1;  q2 = n2;  q3 = n3;  q4 = n4;  q5 = n5;
        q6 = n6;  q7 = n7;  q8 = n8;  q9 = n9;  q10 = n10; q11 = n11;
        q12 = n12; q13 = n13; q14 = n14; q15 = n15;
    }
#undef CSTEP
}

// ---------------------------------------------------------------------------
// Fallback phase-2 (R7-verified, 491us): used if ws too small for masks.
// ---------------------------------------------------------------------------
__global__ __launch_bounds__(64, 1) void snn_recur(
    const float* __restrict__ cur1,
    const float* __restrict__ beta1,
    const float* __restrict__ W2,
    const float* __restrict__ b2,
    const float* __restrict__ beta2,
    const float* __restrict__ W3,
    const float* __restrict__ b3,
    const float* __restrict__ beta3,
    float* __restrict__ out)
{
    __shared__ float sW3T[HH * 21];
    const int lane = threadIdx.x;
    const int b    = blockIdx.x;

    const float* w2p = W2 + lane * HH;
#define W2LD(i) const float4 u##i = *reinterpret_cast<const float4*>(w2p + 4 * i);
    W2LD(0)  W2LD(1)  W2LD(2)  W2LD(3)  W2LD(4)  W2LD(5)  W2LD(6)  W2LD(7)
    W2LD(8)  W2LD(9)  W2LD(10) W2LD(11) W2LD(12) W2LD(13) W2LD(14) W2LD(15)
#undef W2LD

    for (int oo = 0; oo < OO; ++oo) sW3T[lane * 21 + oo] = W3[oo * HH + lane];

    const float bt1 = fminf(fmaxf(beta1[lane], 0.0f), 1.0f);
    const float bb2 = b2[lane];
    const float bt2 = fminf(fmaxf(beta2[lane], 0.0f), 1.0f);
    const int   o   = (lane < OO) ? lane : 0;
    const float bb3 = b3[o];
    const float bt3 = fminf(fmaxf(beta3[o], 0.0f), 1.0f);
    float m1 = 0.0f, m2 = 0.0f, m3 = 0.0f;

    const float* cb   = cur1 + (size_t)b * TT * HH + lane;
    float*       outb = out  + (size_t)b * TT * OO;
    const float* sW3row = sW3T + o;

#define L2J(j, wv) { const float bj = ((s1m >> (j)) & 1ull) ? 1.0f : 0.0f; \
                     c2 = fmaf(bj, (wv), c2); }
#define L2Q(q) L2J(4*(q)+0, u##q.x) L2J(4*(q)+1, u##q.y) \
               L2J(4*(q)+2, u##q.z) L2J(4*(q)+3, u##q.w)

#define STEP(CURV, GVAR) { \
    const float r1v = (m1 > 1.0f) ? 1.0f : 0.0f; \
    m1 = __fsub_rn(__fadd_rn(__fmul_rn(bt1, m1), (CURV)), r1v); \
    const unsigned long long s1m = __ballot(m1 > 1.0f); \
    float c2 = bb2; \
    L2Q(0)  L2Q(1)  L2Q(2)  L2Q(3)  L2Q(4)  L2Q(5)  L2Q(6)  L2Q(7) \
    L2Q(8)  L2Q(9)  L2Q(10) L2Q(11) L2Q(12) L2Q(13) L2Q(14) L2Q(15) \
    const float r2v = (m2 > 1.0f) ? 1.0f : 0.0f; \
    m2 = __fsub_rn(__fadd_rn(__fmul_rn(bt2, m2), c2), r2v); \
    const unsigned long long s2m = __ballot(m2 > 1.0f); \
    float c3 = bb3; \
    if (s2m) { \
        unsigned long long mm = s2m; \
        int jj = __builtin_ctzll(mm); mm &= (mm - 1); \
        float vv = sW3row[jj * 21]; \
        while (mm) { \
            const int j2 = __builtin_ctzll(mm); mm &= (mm - 1); \
            const float v2 = sW3row[j2 * 21]; \
            c3 = __fadd_rn(c3, vv); \
            vv = v2; \
        } \
        c3 = __fadd_rn(c3, vv); \
    } \
    m3 = __fadd_rn(__fmul_rn(bt3, m3), c3); \
    GVAR = m3; \
}

    float q0  = cb[0*HH],  q1  = cb[1*HH],  q2  = cb[2*HH],  q3  = cb[3*HH];
    float q4  = cb[4*HH],  q5  = cb[5*HH],  q6  = cb[6*HH],  q7  = cb[7*HH];
    float q8  = cb[8*HH],  q9  = cb[9*HH],  q10 = cb[10*HH], q11 = cb[11*HH];
    float q12 = cb[12*HH], q13 = cb[13*HH], q14 = cb[14*HH], q15 = cb[15*HH];

#pragma unroll 1
    for (int tb = 0; tb < TT; tb += 16) {
        float n0 = 0.f, n1 = 0.f, n2 = 0.f, n3 = 0.f, n4 = 0.f, n5 = 0.f,
              n6 = 0.f, n7 = 0.f, n8 = 0.f, n9 = 0.f, n10 = 0.f, n11 = 0.f,
              n12 = 0.f, n13 = 0.f, n14 = 0.f, n15 = 0.f;
        if (tb + 16 < TT) {
            const float* cn = cb + (size_t)(tb + 16) * HH;
            n0  = cn[0*HH];  n1  = cn[1*HH];  n2  = cn[2*HH];  n3  = cn[3*HH];
            n4  = cn[4*HH];  n5  = cn[5*HH];  n6  = cn[6*HH];  n7  = cn[7*HH];
            n8  = cn[8*HH];  n9  = cn[9*HH];  n10 = cn[10*HH]; n11 = cn[11*HH];
            n12 = cn[12*HH]; n13 = cn[13*HH]; n14 = cn[14*HH]; n15 = cn[15*HH];
        }

        float g0, g1, g2, g3, g4, g5, g6, g7,
              g8, g9, g10, g11, g12, g13, g14, g15;
        STEP(q0, g0)   STEP(q1, g1)   STEP(q2, g2)   STEP(q3, g3)
        STEP(q4, g4)   STEP(q5, g5)   STEP(q6, g6)   STEP(q7, g7)
        STEP(q8, g8)   STEP(q9, g9)   STEP(q10, g10) STEP(q11, g11)
        STEP(q12, g12) STEP(q13, g13) STEP(q14, g14) STEP(q15, g15)

        if (lane < OO) {
            float* op = outb + (size_t)tb * OO + lane;
            op[0*OO]  = g0;  op[1*OO]  = g1;  op[2*OO]  = g2;  op[3*OO]  = g3;
            op[4*OO]  = g4;  op[5*OO]  = g5;  op[6*OO]  = g6;  op[7*OO]  = g7;
            op[8*OO]  = g8;  op[9*OO]  = g9;  op[10*OO] = g10; op[11*OO] = g11;
            op[12*OO] = g12; op[13*OO] = g13; op[14*OO] = g14; op[15*OO] = g15;
        }

        q0 = n0;  q1 = n1;  q2 = n2;  q3 = n3;  q4 = n4;  q5 = n5;
        q6 = n6;  q7 = n7;  q8 = n8;  q9 = n9;  q10 = n10; q11 = n11;
        q12 = n12; q13 = n13; q14 = n14; q15 = n15;
    }
#undef STEP
#undef L2Q
#undef L2J
}

extern "C" void kernel_launch(void* const* d_in, const int* in_sizes, int n_in,
                              void* d_out, int out_size, void* d_ws, size_t ws_size,
                              hipStream_t stream) {
    const float* x     = (const float*)d_in[0];
    const float* W1    = (const float*)d_in[1];
    const float* b1    = (const float*)d_in[2];
    const float* beta1 = (const float*)d_in[3];
    const float* W2    = (const float*)d_in[4];
    const float* b2    = (const float*)d_in[5];
    const float* beta2 = (const float*)d_in[6];
    const float* W3    = (const float*)d_in[7];
    const float* b3    = (const float*)d_in[8];
    const float* beta3 = (const float*)d_in[9];

    const int B = in_sizes[0] / (TT * DIN);   // 1024
    const int nrows = B * TT;                 // 524288
    const size_t sz_cur1 = (size_t)nrows * HH * sizeof(float);        // 128 MiB
    const size_t sz_mask = (size_t)nrows * sizeof(unsigned long long); // 4 MiB

    if (d_ws != nullptr && ws_size >= sz_cur1 + sz_mask) {
        float* cur1buf = (float*)d_ws;
        unsigned long long* masks =
            (unsigned long long*)((char*)d_ws + sz_cur1);
        snn_cur1<<<dim3(nrows / 64), dim3(256), 0, stream>>>(
            x, W1, b1, cur1buf, nrows);
        snn_spk1<<<dim3(B), dim3(64), 0, stream>>>(cur1buf, beta1, masks);
        snn_cur2<<<dim3(nrows / 128), dim3(256), 0, stream>>>(
            masks, W2, b2, cur1buf /* c2 in place */, nrows);
        snn_rec23<<<dim3(B), dim3(64), 0, stream>>>(
            cur1buf, beta2, W3, b3, beta3, (float*)d_out);
    } else {
        // proven R7 2-kernel path (requires ws >= 128 MiB, verified on harness)
        snn_cur1<<<dim3(nrows / 64), dim3(256), 0, stream>>>(
            x, W1, b1, (float*)d_ws, nrows);
        snn_recur<<<dim3(B), dim3(64), 0, stream>>>(
            (const float*)d_ws, beta1, W2, b2, beta2, W3, b3, beta3,
            (float*)d_out);
    }
}